// Round 3
// baseline (99.734 us; speedup 1.0000x reference)
//
#include <hip/hip_runtime.h>
#include <math.h>

// ---------------- problem constants ----------------
#define P      6400      // SAMPLE*SAMPLE patches per image
#define K      49        // PATCH*PATCH channels (C=1)
#define KP     64        // K padded to MFMA granularity (pad channels are 0)
#define FH     169       // patch-grid H = W = (512-7)/3+1
#define IMG    512
#define EPSF   2.220446049250313e-16f
#define HWT    2.0f      // H_WEIGHT
#define LOCC   0.05f     // LAMBDA_OCC

// ---------------- sweep tiling ----------------
#define CSPLIT 50
#define QCHUNK (P / CSPLIT)           // 128 columns per block; 128 rows per block
#define NSWBLK (CSPLIT * (P / 128))   // 2500 sweep blocks
#define FXSCALE 1099511627776.0       // 2^40 fixed-point scale for Ssum

typedef __attribute__((ext_vector_type(8))) short bf16x8;  // 8 bf16 = 4 VGPR
typedef __attribute__((ext_vector_type(4))) float f32x4;

__device__ inline unsigned bfbits(float x)   // f32 -> bf16 bits, RNE
{
    unsigned u = __float_as_uint(x);
    return (u + 0x7FFFu + ((u >> 16) & 1u)) >> 16;
}

// =====================================================================
// 1) k_prep: (a) init atomic/hist buffers + tickets
//            (b) refer-patch gather -> per-(c, 256-block) partial sums
//    grid = K*P/256 = 1225 blocks; each block lies in one c slice.
// =====================================================================
__global__ void k_prep(const float* __restrict__ rf, const float* __restrict__ rfield,
                       float* __restrict__ ypart,
                       unsigned long long* __restrict__ packed1,
                       int* __restrict__ counts, unsigned* __restrict__ mbits,
                       unsigned long long* __restrict__ Ssum,
                       int* __restrict__ tickets)
{
    int t = threadIdx.x;
    int gid = blockIdx.x * 256 + t;

    // ---- init section (independent buffers, consumed by later kernels)
    if (gid < P) {
        packed1[gid] = 0xFFFFFFFFFFFFFFFFULL;
        counts[gid]  = 0;
        mbits[gid]   = 0xFFFFFFFFu;
        Ssum[gid]    = 0ULL;
    }
    if (gid < 2) tickets[gid] = 0;

    // ---- refer channel-mean partials
    int c = gid / P;
    int p = gid - c * P;             // block fully inside one c (P % 256 == 0)
    float fx = rfield[p * 2 + 0];
    float fy = rfield[p * 2 + 1];
    float gx = fx * 2.0f - 1.0f;
    float gy = fy * 2.0f - 1.0f;
    int ix = (int)rintf(((gx + 1.0f) * (float)FH - 1.0f) * 0.5f);
    int iy = (int)rintf(((gy + 1.0f) * (float)FH - 1.0f) * 0.5f);
    ix = min(max(ix, 0), FH - 1);
    iy = min(max(iy, 0), FH - 1);
    int ky = c / 7, kx = c - ky * 7;
    float v = rf[(iy * 3 + ky) * IMG + (ix * 3 + kx)];

    // wave shuffle reduce (64 lanes), then 4 waves via LDS
    float s = v;
#pragma unroll
    for (int m = 1; m < 64; m <<= 1) s += __shfl_xor(s, m, 64);
    __shared__ float acc4[4];
    int l = t & 63, w = t >> 6;
    if (l == 0) acc4[w] = s;
    __syncthreads();
    if (t == 0) ypart[c * 25 + (p >> 8)] = acc4[0] + acc4[1] + acc4[2] + acc4[3];
}

// =====================================================================
// 2) mean-subtract + L2-normalize + pack to bf16, TRANSPOSED [p][64]
//    Gathers the 49 patch values straight from the image into registers.
//    64-thread blocks x 200: scatter-latency-bound -> spread across CUs.
// =====================================================================
__global__ void k_normpack(const float* __restrict__ tf, const float* __restrict__ rf,
                           const float* __restrict__ tfield, const float* __restrict__ rfield,
                           const float* __restrict__ ypart,
                           unsigned short* __restrict__ tb, unsigned short* __restrict__ rb)
{
    __shared__ float ym[K];
    int t = threadIdx.x;
    if (t < K) {
        float s = 0.f;
#pragma unroll
        for (int i = 0; i < 25; ++i) s += ypart[t * 25 + i];
        ym[t] = s * (1.0f / (float)P);
    }
    __syncthreads();

    int gid = blockIdx.x * 64 + t;       // grid = 2P/64 = 200 blocks
    int sel = gid >= P;
    int p = sel ? gid - P : gid;
    const float* field = sel ? rfield : tfield;
    const float* feat  = sel ? rf : tf;
    unsigned short* ob = sel ? rb : tb;

    float fx = field[p * 2 + 0];
    float fy = field[p * 2 + 1];
    float gx = fx * 2.0f - 1.0f;
    float gy = fy * 2.0f - 1.0f;
    int ix = (int)rintf(((gx + 1.0f) * (float)FH - 1.0f) * 0.5f);
    int iy = (int)rintf(((gy + 1.0f) * (float)FH - 1.0f) * 0.5f);
    ix = min(max(ix, 0), FH - 1);
    iy = min(max(iy, 0), FH - 1);
    const float* base = feat + (iy * 3) * IMG + ix * 3;

    float v[K];
#pragma unroll
    for (int ky = 0; ky < 7; ++ky)
#pragma unroll
        for (int kx = 0; kx < 7; ++kx)
            v[ky * 7 + kx] = base[ky * IMG + kx];

    float ss = 0.f;
#pragma unroll
    for (int c = 0; c < K; ++c) {
        float x = v[c] - ym[c];
        v[c] = x;
        ss += x * x;
    }
    float rn = 1.0f / (sqrtf(ss) + EPSF);

    unsigned wbuf[KP / 2];
#pragma unroll
    for (int i = 0; i < KP / 2; ++i) {
        int c0 = 2 * i, c1 = 2 * i + 1;
        float x0 = (c0 < K) ? v[c0] * rn : 0.f;
        float x1 = (c1 < K) ? v[c1] * rn : 0.f;
        wbuf[i] = (bfbits(x1) << 16) | bfbits(x0);
    }
    uint4* o = (uint4*)(ob + p * KP);    // p*128 bytes: 16B aligned
#pragma unroll
    for (int i = 0; i < KP / 8; ++i)
        o[i] = make_uint4(wbuf[4 * i], wbuf[4 * i + 1], wbuf[4 * i + 2], wbuf[4 * i + 3]);
}

// =====================================================================
// 3) MFMA sim sweeps. block = 4 waves; 128(p) x 128(q) tile; K=64 (2 steps).
//    B tile staged once in LDS, XOR-swizzled in 16B chunks (conflict-free).
//    A/B frag: lane l holds 8 contiguous k at row l&15, k0=(l>>4)*8
//    C/D:      col=l&15, row=(l>>4)*4+reg
//    MODE 1: per-row argmin of d0 (first-occurrence ties) -> atomicMin u64
//            + fused histogram tail: ticket + ATOMIC reads, ZERO fences
//            (R1's 170us regression was wave-wide __threadfence = L2
//            writeback-inv per wave x 10000 waves; atomics-to-atomics
//            needs no fence: both sides act at the device-coherent point)
//    MODE 2: per-row min of d0 + cnt[q]*LOCC              -> atomicMin u32
//    MODE 3: per-row sum exp((1 - d/(m+EPS))*H) -> exact fixed-point
//            atomicAdd into Ssum (deterministic: integer adds commute)
// =====================================================================
template<int MODE>
__global__ __launch_bounds__(256, 4)
void k_sweep(const unsigned short* __restrict__ tb, const unsigned short* __restrict__ rb,
             int* __restrict__ counts, const unsigned* __restrict__ mbits_in,
             unsigned long long* __restrict__ packed1, unsigned* __restrict__ mbits_out,
             unsigned long long* __restrict__ Ssum, int* __restrict__ ticket)
{
    __shared__ uint4 bs[1024];           // 16 KB: 128 rows x 8 chunks of 16B
    const int p0 = blockIdx.x * 128, q0 = blockIdx.y * QCHUNK;
    const int t  = threadIdx.x;
    const int w  = t >> 6, l = t & 63;
    const int l15 = l & 15, lg = l >> 4;

    // A fragments: issue global loads first so they overlap the staging
    bf16x8 afr[2][2];
#pragma unroll
    for (int mt = 0; mt < 2; ++mt)
#pragma unroll
        for (int ks = 0; ks < 2; ++ks)
            afr[mt][ks] = *(const bf16x8*)(tb + (p0 + w * 32 + mt * 16 + l15) * KP + ks * 32 + lg * 8);

    // ---- stage B tile: 1024 16B chunks; 4 per thread, XOR-swizzled write
    {
        const int r = t >> 1;            // 2 threads per row, 4 chunks each
        const int cbase = (t & 1) * 4;
        const uint4* src = (const uint4*)(rb + (q0 + r) * KP);
#pragma unroll
        for (int i = 0; i < 4; ++i) {
            int c = cbase + i;
            bs[r * 8 + (c ^ (r & 7))] = src[c];
        }
    }
    __syncthreads();

    f32x4 acc[2][8];
#pragma unroll
    for (int mt = 0; mt < 2; ++mt)
#pragma unroll
        for (int qt = 0; qt < 8; ++qt) acc[mt][qt] = (f32x4){0.f, 0.f, 0.f, 0.f};

#pragma unroll
    for (int qt = 0; qt < 8; ++qt) {
        const int row = qt * 16 + l15;
        bf16x8 b0 = *(const bf16x8*)&bs[row * 8 + ((0 + lg) ^ (row & 7))];
        bf16x8 b1 = *(const bf16x8*)&bs[row * 8 + ((4 + lg) ^ (row & 7))];
#pragma unroll
        for (int mt = 0; mt < 2; ++mt) {
            acc[mt][qt] = __builtin_amdgcn_mfma_f32_16x16x32_bf16(afr[mt][0], b0, acc[mt][qt], 0, 0, 0);
            acc[mt][qt] = __builtin_amdgcn_mfma_f32_16x16x32_bf16(afr[mt][1], b1, acc[mt][qt], 0, 0, 0);
        }
    }

    float osv[8];
    if (MODE >= 2) {
#pragma unroll
        for (int qt = 0; qt < 8; ++qt) osv[qt] = (float)counts[q0 + qt * 16 + l15] * LOCC;
    }

#pragma unroll
    for (int mt = 0; mt < 2; ++mt) {
#pragma unroll
        for (int r = 0; r < 4; ++r) {
            int p = p0 + w * 32 + mt * 16 + lg * 4 + r;
            float rinv = 0.f;
            if (MODE == 3) rinv = 1.0f / (__uint_as_float(mbits_in[p]) + EPSF);

            float bv = 1e30f; int bi = 0; float s = 0.f;
#pragma unroll
            for (int qt = 0; qt < 8; ++qt) {    // qt ascending -> q ascending per lane
                float d = fmaxf((1.0f - acc[mt][qt][r]) * 0.5f, 0.0f);
                if (MODE >= 2) d += osv[qt];
                if (MODE == 1) {
                    bool upd = d < bv;          // strict <: first occurrence wins
                    bi = upd ? (q0 + qt * 16 + l15) : bi;
                    bv = upd ? d : bv;
                } else if (MODE == 2) {
                    bv = fminf(bv, d);
                } else {
                    s += __expf((1.0f - d * rinv) * HWT);
                }
            }

            // reduce across the 16 lanes of this row group (masks 1,2,4,8)
            if (MODE == 1) {
                // packed (value,index) lexicographic min: d >= 0 so f32 bits
                // are order-preserving; ties -> smaller q.
                unsigned long long enc =
                    ((unsigned long long)__float_as_uint(bv) << 32) | (unsigned)bi;
#pragma unroll
                for (int m = 1; m < 16; m <<= 1) {
                    unsigned long long o = __shfl_xor(enc, m, 64);
                    enc = (o < enc) ? o : enc;
                }
                if (l15 == 0) atomicMin(&packed1[p], enc);
            } else if (MODE == 2) {
#pragma unroll
                for (int m = 1; m < 16; m <<= 1) bv = fminf(bv, __shfl_xor(bv, m, 64));
                if (l15 == 0) atomicMin(&mbits_out[p], __float_as_uint(bv));
            } else {
#pragma unroll
                for (int m = 1; m < 16; m <<= 1) s += __shfl_xor(s, m, 64);
                if (l15 == 0) {
                    // exact fixed-point: (double)s * 2^40 is exact (24-bit
                    // mantissa, s <= 128*e^0 -> product < 2^47)
                    double sd = (double)s * FXSCALE + 0.5;
                    atomicAdd(&Ssum[p], (unsigned long long)sd);
                }
            }
        }
    }

    // ---- fused histogram (MODE 1 only): last block replays packed1.
    // No fences anywhere: block's atomicMins are drained by the waitcnt
    // the compiler emits before s_barrier; ticket and replay reads are
    // atomics at the same coherence point.
    if (MODE == 1) {
        __syncthreads();
        __shared__ int lastblk;
        if (t == 0) lastblk = (atomicAdd(ticket, 1) == NSWBLK - 1);
        __syncthreads();
        if (lastblk) {
            for (int pp = t; pp < P; pp += 256) {
                unsigned long long v = atomicAdd(&packed1[pp], 0ULL);  // coherent read
                atomicAdd(&counts[(unsigned)(v & 0xffffffffULL)], 1);
            }
        }
    }
}

// =====================================================================
// 4) epilogue: per-row -log(CX), block partials, last block finishes
//    (deterministic: last block sums the 50 partials in index order)
// =====================================================================
__global__ void k_loss(const unsigned long long* __restrict__ Ssum,
                       const unsigned* __restrict__ mbits,
                       float* __restrict__ partial, int* __restrict__ ticket,
                       float* __restrict__ out)
{
    int b = blockIdx.x, t = threadIdx.x;   // 50 blocks x 128 threads
    int p = b * 128 + t;
    float s = (float)((double)Ssum[p] * (1.0 / FXSCALE));
    float m = __uint_as_float(mbits[p]);
    float lw = (1.0f - m / (m + EPSF)) * HWT;   // log of max weight
    float v = logf(s) - lw;                      // -log(CX)
    __shared__ float red[128];
    red[t] = v; __syncthreads();
    for (int w = 64; w > 0; w >>= 1) { if (t < w) red[t] += red[t + w]; __syncthreads(); }

    __shared__ int lastblk;
    if (t == 0) {
        atomicExch(&partial[b], red[0]);   // device-scope write (coherent point)
        __threadfence();                   // single thread x 50 blocks: noise
        lastblk = (atomicAdd(ticket, 1) == CSPLIT - 1);
    }
    __syncthreads();
    if (lastblk && t < 64) {
        float x = (t < CSPLIT) ? atomicAdd(&partial[t], 0.0f) : 0.f;  // atomic read
#pragma unroll
        for (int mm = 32; mm > 0; mm >>= 1) x += __shfl_down(x, mm, 64);
        if (t == 0) out[0] = x * (1.0f / (float)P);
    }
}

// =====================================================================
extern "C" void kernel_launch(void* const* d_in, const int* in_sizes, int n_in,
                              void* d_out, int out_size, void* d_ws, size_t ws_size,
                              hipStream_t stream)
{
    const float* tf  = (const float*)d_in[0];
    const float* rf  = (const float*)d_in[1];
    const float* tfd = (const float*)d_in[2];
    const float* rfd = (const float*)d_in[3];
    float* out = (float*)d_out;

    float* ws = (float*)d_ws;
    float* ypart = ws;                                       // K*25 = 1225 f
    unsigned short* tb = (unsigned short*)(ws + 2048);       // P*KP bf16 = 204800 f
    unsigned short* rb = (unsigned short*)(ws + 206848);     // P*KP bf16 = 204800 f
    unsigned long long* packed1 = (unsigned long long*)(ws + 411648); // P u64 = 12800 f
    unsigned long long* Ssum    = (unsigned long long*)(ws + 424448); // P u64 = 12800 f
    int*      counts  = (int*)(ws + 437248);                 // P
    unsigned* mbits   = (unsigned*)(ws + 443648);            // P
    float*    partial = ws + 450048;                         // 64
    int*      tickets = (int*)(ws + 450112);                 // 2
    // total ~450114 floats ~= 1.8 MB

    // 6 kernels: prep | normpack | sweep1+hist | sweep2 | sweep3 | loss+final
    k_prep<<<K * P / 256, 256, 0, stream>>>(rf, rfd, ypart, packed1, counts, mbits, Ssum, tickets);
    k_normpack<<<2 * P / 64, 64, 0, stream>>>(tf, rf, tfd, rfd, ypart, tb, rb);

    dim3 g(P / 128, CSPLIT);
    k_sweep<1><<<g, 256, 0, stream>>>(tb, rb, counts, nullptr, packed1, nullptr, nullptr, &tickets[0]);
    k_sweep<2><<<g, 256, 0, stream>>>(tb, rb, counts, nullptr, nullptr, mbits, nullptr, nullptr);
    k_sweep<3><<<g, 256, 0, stream>>>(tb, rb, counts, mbits, nullptr, nullptr, Ssum, nullptr);

    k_loss<<<CSPLIT, 128, 0, stream>>>(Ssum, mbits, partial, &tickets[1], out);
}

// Round 4
// 87.443 us; speedup vs baseline: 1.1406x; 1.1406x over previous
//
#include <hip/hip_runtime.h>
#include <math.h>

// ---------------- problem constants ----------------
#define P      6400      // SAMPLE*SAMPLE patches per image
#define K      49        // PATCH*PATCH channels (C=1)
#define KP     64        // K padded to MFMA granularity (pad channels are 0)
#define FH     169       // patch-grid H = W = (512-7)/3+1
#define IMG    512
#define EPSF   2.220446049250313e-16f
#define HWT    2.0f      // H_WEIGHT
#define LOCC   0.05f     // LAMBDA_OCC

// ---------------- sweep tiling ----------------
#define CSPLIT 50
#define QCHUNK (P / CSPLIT)           // 128 columns per block; 128 rows per block
#define FXSCALE 1099511627776.0       // 2^40 fixed-point scale for Ssum

typedef __attribute__((ext_vector_type(8))) short bf16x8;  // 8 bf16 = 4 VGPR
typedef __attribute__((ext_vector_type(4))) float f32x4;

__device__ inline unsigned bfbits(float x)   // f32 -> bf16 bits, RNE
{
    unsigned u = __float_as_uint(x);
    return (u + 0x7FFFu + ((u >> 16) & 1u)) >> 16;
}

// =====================================================================
// 1) k_prep: (a) init atomic buffers + ticket
//            (b) refer-patch gather -> per-(c, 256-block) partial sums
//    grid = K*P/256 = 1225 blocks; each block lies in one c slice.
// =====================================================================
__global__ void k_prep(const float* __restrict__ rf, const float* __restrict__ rfield,
                       float* __restrict__ ypart,
                       unsigned long long* __restrict__ packed1,
                       unsigned* __restrict__ mbits,
                       unsigned long long* __restrict__ Ssum,
                       int* __restrict__ ticket)
{
    int t = threadIdx.x;
    int gid = blockIdx.x * 256 + t;

    // ---- init section (independent buffers, consumed by later kernels)
    if (gid < P) {
        packed1[gid] = 0xFFFFFFFFFFFFFFFFULL;
        mbits[gid]   = 0xFFFFFFFFu;
        Ssum[gid]    = 0ULL;
    }
    if (gid == 0) ticket[0] = 0;

    // ---- refer channel-mean partials
    int c = gid / P;
    int p = gid - c * P;             // block fully inside one c (P % 256 == 0)
    float fx = rfield[p * 2 + 0];
    float fy = rfield[p * 2 + 1];
    float gx = fx * 2.0f - 1.0f;
    float gy = fy * 2.0f - 1.0f;
    int ix = (int)rintf(((gx + 1.0f) * (float)FH - 1.0f) * 0.5f);
    int iy = (int)rintf(((gy + 1.0f) * (float)FH - 1.0f) * 0.5f);
    ix = min(max(ix, 0), FH - 1);
    iy = min(max(iy, 0), FH - 1);
    int ky = c / 7, kx = c - ky * 7;
    float v = rf[(iy * 3 + ky) * IMG + (ix * 3 + kx)];

    // wave shuffle reduce (64 lanes), then 4 waves via LDS
    float s = v;
#pragma unroll
    for (int m = 1; m < 64; m <<= 1) s += __shfl_xor(s, m, 64);
    __shared__ float acc4[4];
    int l = t & 63, w = t >> 6;
    if (l == 0) acc4[w] = s;
    __syncthreads();
    if (t == 0) ypart[c * 25 + (p >> 8)] = acc4[0] + acc4[1] + acc4[2] + acc4[3];
}

// =====================================================================
// 2) mean-subtract + L2-normalize + pack to bf16, TRANSPOSED [p][64]
//    Gathers the 49 patch values straight from the image into registers.
//    64-thread blocks x 200: scatter-latency-bound -> spread across CUs.
// =====================================================================
__global__ void k_normpack(const float* __restrict__ tf, const float* __restrict__ rf,
                           const float* __restrict__ tfield, const float* __restrict__ rfield,
                           const float* __restrict__ ypart,
                           unsigned short* __restrict__ tb, unsigned short* __restrict__ rb)
{
    __shared__ float ym[K];
    int t = threadIdx.x;
    if (t < K) {
        float s = 0.f;
#pragma unroll
        for (int i = 0; i < 25; ++i) s += ypart[t * 25 + i];
        ym[t] = s * (1.0f / (float)P);
    }
    __syncthreads();

    int gid = blockIdx.x * 64 + t;       // grid = 2P/64 = 200 blocks
    int sel = gid >= P;
    int p = sel ? gid - P : gid;
    const float* field = sel ? rfield : tfield;
    const float* feat  = sel ? rf : tf;
    unsigned short* ob = sel ? rb : tb;

    float fx = field[p * 2 + 0];
    float fy = field[p * 2 + 1];
    float gx = fx * 2.0f - 1.0f;
    float gy = fy * 2.0f - 1.0f;
    int ix = (int)rintf(((gx + 1.0f) * (float)FH - 1.0f) * 0.5f);
    int iy = (int)rintf(((gy + 1.0f) * (float)FH - 1.0f) * 0.5f);
    ix = min(max(ix, 0), FH - 1);
    iy = min(max(iy, 0), FH - 1);
    const float* base = feat + (iy * 3) * IMG + ix * 3;

    float v[K];
#pragma unroll
    for (int ky = 0; ky < 7; ++ky)
#pragma unroll
        for (int kx = 0; kx < 7; ++kx)
            v[ky * 7 + kx] = base[ky * IMG + kx];

    float ss = 0.f;
#pragma unroll
    for (int c = 0; c < K; ++c) {
        float x = v[c] - ym[c];
        v[c] = x;
        ss += x * x;
    }
    float rn = 1.0f / (sqrtf(ss) + EPSF);

    unsigned wbuf[KP / 2];
#pragma unroll
    for (int i = 0; i < KP / 2; ++i) {
        int c0 = 2 * i, c1 = 2 * i + 1;
        float x0 = (c0 < K) ? v[c0] * rn : 0.f;
        float x1 = (c1 < K) ? v[c1] * rn : 0.f;
        wbuf[i] = (bfbits(x1) << 16) | bfbits(x0);
    }
    uint4* o = (uint4*)(ob + p * KP);    // p*128 bytes: 16B aligned
#pragma unroll
    for (int i = 0; i < KP / 8; ++i)
        o[i] = make_uint4(wbuf[4 * i], wbuf[4 * i + 1], wbuf[4 * i + 2], wbuf[4 * i + 3]);
}

// =====================================================================
// 3) MFMA sim sweeps. block = 4 waves; 128(p) x 128(q) tile; K=64 (2 steps).
//    B tile staged once in LDS, XOR-swizzled in 16B chunks (conflict-free).
//    A/B frag: lane l holds 8 contiguous k at row l&15, k0=(l>>4)*8
//    C/D:      col=l&15, row=(l>>4)*4+reg
//
//    Occurrence weights WITHOUT a global histogram kernel:
//      T_THR=1.0 -> thr = counts.max() -> the (counts<=thr) filter is a
//      no-op; omega = P1/P2 = 1  =>  occur[q] == (float)counts[q].
//      counts[q] = #{p : argmin_idx(p) == q}. Each block needs only its
//      own 128 columns -> private 128-bin LDS histogram built by scanning
//      packed1's low words (51 KB, L2-resident; ~128 LDS-atomic hits).
//
//    MODE 1: per-row argmin of d0 (first-occurrence ties) -> atomicMin u64
//    MODE 2: local hist; per-row min of d0 + cnt[q]*LOCC  -> atomicMin u32
//    MODE 3: local hist; per-row sum exp((1 - d/(m+EPS))*H) -> exact
//            fixed-point atomicAdd into Ssum (integer adds commute ->
//            deterministic)
// =====================================================================
template<int MODE>
__global__ __launch_bounds__(256, 4)
void k_sweep(const unsigned short* __restrict__ tb, const unsigned short* __restrict__ rb,
             unsigned long long* __restrict__ packed1, unsigned* __restrict__ mbits,
             unsigned long long* __restrict__ Ssum)
{
    __shared__ uint4 bs[1024];           // 16 KB: 128 rows x 8 chunks of 16B
    __shared__ int cnt[QCHUNK];          // 128-bin local histogram (MODE>=2)
    const int p0 = blockIdx.x * 128, q0 = blockIdx.y * QCHUNK;
    const int t  = threadIdx.x;
    const int w  = t >> 6, l = t & 63;
    const int l15 = l & 15, lg = l >> 4;

    // A fragments: issue global loads first so they overlap the staging
    bf16x8 afr[2][2];
#pragma unroll
    for (int mt = 0; mt < 2; ++mt)
#pragma unroll
        for (int ks = 0; ks < 2; ++ks)
            afr[mt][ks] = *(const bf16x8*)(tb + (p0 + w * 32 + mt * 16 + l15) * KP + ks * 32 + lg * 8);

    // ---- stage B tile: 1024 16B chunks; 4 per thread, XOR-swizzled write
    {
        const int r = t >> 1;            // 2 threads per row, 4 chunks each
        const int cbase = (t & 1) * 4;
        const uint4* src = (const uint4*)(rb + (q0 + r) * KP);
#pragma unroll
        for (int i = 0; i < 4; ++i) {
            int c = cbase + i;
            bs[r * 8 + (c ^ (r & 7))] = src[c];
        }
    }
    if (MODE >= 2 && t < QCHUNK) cnt[t] = 0;
    __syncthreads();

    // ---- local histogram scan (MODE>=2): 25 low-words per thread
    if (MODE >= 2) {
        const unsigned* pk32 = (const unsigned*)packed1;
#pragma unroll
        for (int i = 0; i < P / 256; ++i) {
            unsigned idx = pk32[2 * (i * 256 + t)];       // low word = argmin q
            unsigned rel = idx - (unsigned)q0;
            if (rel < (unsigned)QCHUNK) atomicAdd(&cnt[rel], 1);
        }
    }

    f32x4 acc[2][8];
#pragma unroll
    for (int mt = 0; mt < 2; ++mt)
#pragma unroll
        for (int qt = 0; qt < 8; ++qt) acc[mt][qt] = (f32x4){0.f, 0.f, 0.f, 0.f};

#pragma unroll
    for (int qt = 0; qt < 8; ++qt) {
        const int row = qt * 16 + l15;
        bf16x8 b0 = *(const bf16x8*)&bs[row * 8 + ((0 + lg) ^ (row & 7))];
        bf16x8 b1 = *(const bf16x8*)&bs[row * 8 + ((4 + lg) ^ (row & 7))];
#pragma unroll
        for (int mt = 0; mt < 2; ++mt) {
            acc[mt][qt] = __builtin_amdgcn_mfma_f32_16x16x32_bf16(afr[mt][0], b0, acc[mt][qt], 0, 0, 0);
            acc[mt][qt] = __builtin_amdgcn_mfma_f32_16x16x32_bf16(afr[mt][1], b1, acc[mt][qt], 0, 0, 0);
        }
    }

    float osv[8];
    if (MODE >= 2) {
        __syncthreads();                 // histogram complete
#pragma unroll
        for (int qt = 0; qt < 8; ++qt) osv[qt] = (float)cnt[qt * 16 + l15] * LOCC;
    }

#pragma unroll
    for (int mt = 0; mt < 2; ++mt) {
#pragma unroll
        for (int r = 0; r < 4; ++r) {
            int p = p0 + w * 32 + mt * 16 + lg * 4 + r;
            float rinv = 0.f;
            if (MODE == 3) rinv = 1.0f / (__uint_as_float(mbits[p]) + EPSF);

            float bv = 1e30f; int bi = 0; float s = 0.f;
#pragma unroll
            for (int qt = 0; qt < 8; ++qt) {    // qt ascending -> q ascending per lane
                float d = fmaxf((1.0f - acc[mt][qt][r]) * 0.5f, 0.0f);
                if (MODE >= 2) d += osv[qt];
                if (MODE == 1) {
                    bool upd = d < bv;          // strict <: first occurrence wins
                    bi = upd ? (q0 + qt * 16 + l15) : bi;
                    bv = upd ? d : bv;
                } else if (MODE == 2) {
                    bv = fminf(bv, d);
                } else {
                    s += __expf((1.0f - d * rinv) * HWT);
                }
            }

            // reduce across the 16 lanes of this row group (masks 1,2,4,8)
            if (MODE == 1) {
                // packed (value,index) lexicographic min: d >= 0 so f32 bits
                // are order-preserving; ties -> smaller q.
                unsigned long long enc =
                    ((unsigned long long)__float_as_uint(bv) << 32) | (unsigned)bi;
#pragma unroll
                for (int m = 1; m < 16; m <<= 1) {
                    unsigned long long o = __shfl_xor(enc, m, 64);
                    enc = (o < enc) ? o : enc;
                }
                if (l15 == 0) atomicMin(&packed1[p], enc);
            } else if (MODE == 2) {
#pragma unroll
                for (int m = 1; m < 16; m <<= 1) bv = fminf(bv, __shfl_xor(bv, m, 64));
                if (l15 == 0) atomicMin(&mbits[p], __float_as_uint(bv));
            } else {
#pragma unroll
                for (int m = 1; m < 16; m <<= 1) s += __shfl_xor(s, m, 64);
                if (l15 == 0) {
                    // exact fixed-point: (double)s * 2^40 is exact
                    // (s <= 128 -> product < 2^47); row total < 2^53
                    double sd = (double)s * FXSCALE + 0.5;
                    atomicAdd(&Ssum[p], (unsigned long long)sd);
                }
            }
        }
    }
}

// =====================================================================
// 4) epilogue: per-row -log(CX), block partials, last block finishes
//    (deterministic: last block sums the 50 partials in index order;
//    fence here is 1 thread x 50 blocks -> noise)
// =====================================================================
__global__ void k_loss(const unsigned long long* __restrict__ Ssum,
                       const unsigned* __restrict__ mbits,
                       float* __restrict__ partial, int* __restrict__ ticket,
                       float* __restrict__ out)
{
    int b = blockIdx.x, t = threadIdx.x;   // 50 blocks x 128 threads
    int p = b * 128 + t;
    float s = (float)((double)Ssum[p] * (1.0 / FXSCALE));
    float m = __uint_as_float(mbits[p]);
    float lw = (1.0f - m / (m + EPSF)) * HWT;   // log of max weight
    float v = logf(s) - lw;                      // -log(CX)
    __shared__ float red[128];
    red[t] = v; __syncthreads();
    for (int w = 64; w > 0; w >>= 1) { if (t < w) red[t] += red[t + w]; __syncthreads(); }

    __shared__ int lastblk;
    if (t == 0) {
        atomicExch(&partial[b], red[0]);   // device-scope write (coherent point)
        __threadfence();
        lastblk = (atomicAdd(ticket, 1) == CSPLIT - 1);
    }
    __syncthreads();
    if (lastblk && t < 64) {
        float x = (t < CSPLIT) ? atomicAdd(&partial[t], 0.0f) : 0.f;  // atomic read
#pragma unroll
        for (int mm = 32; mm > 0; mm >>= 1) x += __shfl_down(x, mm, 64);
        if (t == 0) out[0] = x * (1.0f / (float)P);
    }
}

// =====================================================================
extern "C" void kernel_launch(void* const* d_in, const int* in_sizes, int n_in,
                              void* d_out, int out_size, void* d_ws, size_t ws_size,
                              hipStream_t stream)
{
    const float* tf  = (const float*)d_in[0];
    const float* rf  = (const float*)d_in[1];
    const float* tfd = (const float*)d_in[2];
    const float* rfd = (const float*)d_in[3];
    float* out = (float*)d_out;

    float* ws = (float*)d_ws;
    float* ypart = ws;                                       // K*25 = 1225 f
    unsigned short* tb = (unsigned short*)(ws + 2048);       // P*KP bf16 = 204800 f
    unsigned short* rb = (unsigned short*)(ws + 206848);     // P*KP bf16 = 204800 f
    unsigned long long* packed1 = (unsigned long long*)(ws + 411648); // P u64 = 12800 f
    unsigned long long* Ssum    = (unsigned long long*)(ws + 424448); // P u64 = 12800 f
    unsigned* mbits   = (unsigned*)(ws + 437248);            // P
    float*    partial = ws + 443648;                         // 64
    int*      ticket  = (int*)(ws + 443712);                 // 1
    // total ~443713 floats ~= 1.8 MB

    // 6 kernels: prep | normpack | sweep1 | sweep2(+hist) | sweep3(+hist) | loss
    k_prep<<<K * P / 256, 256, 0, stream>>>(rf, rfd, ypart, packed1, mbits, Ssum, ticket);
    k_normpack<<<2 * P / 64, 64, 0, stream>>>(tf, rf, tfd, rfd, ypart, tb, rb);

    dim3 g(P / 128, CSPLIT);
    k_sweep<1><<<g, 256, 0, stream>>>(tb, rb, packed1, nullptr, nullptr);
    k_sweep<2><<<g, 256, 0, stream>>>(tb, rb, packed1, mbits, nullptr);
    k_sweep<3><<<g, 256, 0, stream>>>(tb, rb, packed1, mbits, Ssum);

    k_loss<<<CSPLIT, 128, 0, stream>>>(Ssum, mbits, partial, ticket, out);
}